// Round 1
// baseline (380.895 us; speedup 1.0000x reference)
//
#include <hip/hip_runtime.h>

// loss = a*sum(pn^2) + 2*sum(z)*sum(pn) + sum(z^2)*(N - a)
//   where z = (margin - p) on positives, pn = p on negatives, a = #positives.
// Memory-bound streaming reduction: 256 MiB read, one scalar out.

constexpr float MARGIN = 1.0f;

__device__ __forceinline__ float wave_reduce(float v) {
    // full 64-lane wave reduction
    #pragma unroll
    for (int off = 32; off > 0; off >>= 1) v += __shfl_down(v, off, 64);
    return v;
}

__global__ __launch_bounds__(256) void hinge2_reduce(
    const float* __restrict__ pred, const int* __restrict__ lab,
    float* __restrict__ ws, int nvec)
{
    const float4* p4 = reinterpret_cast<const float4*>(pred);
    const int4*   l4 = reinterpret_cast<const int4*>(lab);

    float a = 0.f, sz = 0.f, sz2 = 0.f, sp = 0.f, sp2 = 0.f;

    int idx    = blockIdx.x * blockDim.x + threadIdx.x;
    int stride = gridDim.x * blockDim.x;

    for (int i = idx; i < nvec; i += stride) {
        float4 p = p4[i];
        int4   l = l4[i];
        // branch-free masked accumulation
        #define ACC(px, lx) do {                         \
            float ispos = ((lx) == 1) ? 1.0f : 0.0f;     \
            float z  = ispos * (MARGIN - (px));          \
            a   += ispos;                                \
            sz  += z;                                    \
            sz2 += z * z;                                \
            float pn = (px) - ispos * (px);              \
            sp  += pn;                                   \
            sp2 += pn * pn;                              \
        } while (0)
        ACC(p.x, l.x); ACC(p.y, l.y); ACC(p.z, l.z); ACC(p.w, l.w);
        #undef ACC
    }

    // wave-level reduce
    a   = wave_reduce(a);
    sz  = wave_reduce(sz);
    sz2 = wave_reduce(sz2);
    sp  = wave_reduce(sp);
    sp2 = wave_reduce(sp2);

    __shared__ float sdata[4][5];   // 4 waves per 256-thread block
    int lane = threadIdx.x & 63;
    int wid  = threadIdx.x >> 6;
    if (lane == 0) {
        sdata[wid][0] = a;
        sdata[wid][1] = sz;
        sdata[wid][2] = sz2;
        sdata[wid][3] = sp;
        sdata[wid][4] = sp2;
    }
    __syncthreads();

    if (threadIdx.x == 0) {
        float t0 = 0.f, t1 = 0.f, t2 = 0.f, t3 = 0.f, t4 = 0.f;
        #pragma unroll
        for (int w = 0; w < 4; ++w) {
            t0 += sdata[w][0];
            t1 += sdata[w][1];
            t2 += sdata[w][2];
            t3 += sdata[w][3];
            t4 += sdata[w][4];
        }
        atomicAdd(&ws[0], t0);
        atomicAdd(&ws[1], t1);
        atomicAdd(&ws[2], t2);
        atomicAdd(&ws[3], t3);
        atomicAdd(&ws[4], t4);
    }
}

__global__ void hinge2_final(const float* __restrict__ ws,
                             const float* __restrict__ pred,
                             const int* __restrict__ lab,
                             float* __restrict__ out, int n, int tail_start)
{
    double a   = ws[0];
    double sz  = ws[1];
    double sz2 = ws[2];
    double sp  = ws[3];
    double sp2 = ws[4];

    // handle non-multiple-of-4 tail (none for N = 2^25, but stay general)
    for (int i = tail_start; i < n; ++i) {
        float p = pred[i];
        if (lab[i] == 1) {
            double z = (double)MARGIN - (double)p;
            a += 1.0; sz += z; sz2 += z * z;
        } else {
            sp += (double)p; sp2 += (double)p * (double)p;
        }
    }

    double nneg = (double)n - a;
    double loss = a * sp2 + 2.0 * sz * sp + sz2 * nneg;
    out[0] = (float)loss;
}

extern "C" void kernel_launch(void* const* d_in, const int* in_sizes, int n_in,
                              void* d_out, int out_size, void* d_ws, size_t ws_size,
                              hipStream_t stream)
{
    const float* pred = (const float*)d_in[0];
    const int*   lab  = (const int*)d_in[1];
    float*       out  = (float*)d_out;
    float*       ws   = (float*)d_ws;

    int n    = in_sizes[0];
    int nvec = n >> 2;          // float4 / int4 groups
    int tail = nvec << 2;

    // ws is re-poisoned to 0xAA before every timed launch — zero the accumulators.
    hipMemsetAsync(ws, 0, 5 * sizeof(float), stream);

    const int block  = 256;
    const int blocks = 2048;    // 2048*4 waves = 32 waves/CU across 256 CUs
    hinge2_reduce<<<blocks, block, 0, stream>>>(pred, lab, ws, nvec);
    hinge2_final<<<1, 1, 0, stream>>>(ws, pred, lab, out, n, tail);
}

// Round 2
// 285.036 us; speedup vs baseline: 1.3363x; 1.3363x over previous
//
#include <hip/hip_runtime.h>

// loss = a*sum(pn^2) + 2*sum(z)*sum(pn) + sum(z^2)*(N - a)
//   where z = (margin - p) on positives, pn = p on negatives, a = #positives.
// Streaming reduction: 256 MiB read, one scalar out. Memory-bound.
//
// R1 post-mortem: 205us with VALUBusy=6%, HBM=8% -> stall was the 10240
// same-cache-line atomicAdds (5 floats, one L2 line, 2048 blocks) plus only
// 2 loads in flight per wave. R2: 256 atomic banks (128-B apart) + 4x unroll.

constexpr float MARGIN = 1.0f;

#define BANK_STRIDE 32   // floats; 128 B = one L2 line per bank

__device__ __forceinline__ float wave_reduce(float v) {
    #pragma unroll
    for (int off = 32; off > 0; off >>= 1) v += __shfl_down(v, off, 64);
    return v;
}

__global__ __launch_bounds__(256) void hinge2_reduce(
    const float* __restrict__ pred, const int* __restrict__ lab,
    float* __restrict__ ws, int nvec, int nbanks, int bank_stride)
{
    const float4* p4 = reinterpret_cast<const float4*>(pred);
    const int4*   l4 = reinterpret_cast<const int4*>(lab);

    float a = 0.f, sz = 0.f, sz2 = 0.f, sp = 0.f, sp2 = 0.f;

    int idx    = blockIdx.x * blockDim.x + threadIdx.x;
    int stride = gridDim.x * blockDim.x;

    #define ACC(px, lx) do {                         \
        float ispos = ((lx) == 1) ? 1.0f : 0.0f;     \
        float z  = ispos * (MARGIN - (px));          \
        a   += ispos;                                \
        sz  += z;                                    \
        sz2 += z * z;                                \
        float pn = (px) - ispos * (px);              \
        sp  += pn;                                   \
        sp2 += pn * pn;                              \
    } while (0)

    int i = idx;
    // 4x unroll: 8 independent 16-B loads in flight per wave before first use
    for (; i + 3 * stride < nvec; i += 4 * stride) {
        float4 p0 = p4[i];
        float4 p1 = p4[i + stride];
        float4 p2 = p4[i + 2 * stride];
        float4 p3 = p4[i + 3 * stride];
        int4   l0 = l4[i];
        int4   l1 = l4[i + stride];
        int4   l2 = l4[i + 2 * stride];
        int4   l3 = l4[i + 3 * stride];
        ACC(p0.x, l0.x); ACC(p0.y, l0.y); ACC(p0.z, l0.z); ACC(p0.w, l0.w);
        ACC(p1.x, l1.x); ACC(p1.y, l1.y); ACC(p1.z, l1.z); ACC(p1.w, l1.w);
        ACC(p2.x, l2.x); ACC(p2.y, l2.y); ACC(p2.z, l2.z); ACC(p2.w, l2.w);
        ACC(p3.x, l3.x); ACC(p3.y, l3.y); ACC(p3.z, l3.z); ACC(p3.w, l3.w);
    }
    for (; i < nvec; i += stride) {
        float4 p = p4[i];
        int4   l = l4[i];
        ACC(p.x, l.x); ACC(p.y, l.y); ACC(p.z, l.z); ACC(p.w, l.w);
    }
    #undef ACC

    a   = wave_reduce(a);
    sz  = wave_reduce(sz);
    sz2 = wave_reduce(sz2);
    sp  = wave_reduce(sp);
    sp2 = wave_reduce(sp2);

    __shared__ float sdata[4][5];
    int lane = threadIdx.x & 63;
    int wid  = threadIdx.x >> 6;
    if (lane == 0) {
        sdata[wid][0] = a;
        sdata[wid][1] = sz;
        sdata[wid][2] = sz2;
        sdata[wid][3] = sp;
        sdata[wid][4] = sp2;
    }
    __syncthreads();

    if (threadIdx.x == 0) {
        float t0 = 0.f, t1 = 0.f, t2 = 0.f, t3 = 0.f, t4 = 0.f;
        #pragma unroll
        for (int w = 0; w < 4; ++w) {
            t0 += sdata[w][0];
            t1 += sdata[w][1];
            t2 += sdata[w][2];
            t3 += sdata[w][3];
            t4 += sdata[w][4];
        }
        // spread contention: one 128-B line per bank, ~8 atomics per bank
        float* bank = ws + (blockIdx.x & (nbanks - 1)) * bank_stride;
        atomicAdd(&bank[0], t0);
        atomicAdd(&bank[1], t1);
        atomicAdd(&bank[2], t2);
        atomicAdd(&bank[3], t3);
        atomicAdd(&bank[4], t4);
    }
}

__global__ __launch_bounds__(256) void hinge2_final(
    const float* __restrict__ ws,
    const float* __restrict__ pred, const int* __restrict__ lab,
    float* __restrict__ out, int n, int tail_start,
    int nbanks, int bank_stride)
{
    int t = threadIdx.x;
    float a = 0.f, sz = 0.f, sz2 = 0.f, sp = 0.f, sp2 = 0.f;
    for (int b = t; b < nbanks; b += 256) {
        const float* bank = ws + b * bank_stride;
        a   += bank[0];
        sz  += bank[1];
        sz2 += bank[2];
        sp  += bank[3];
        sp2 += bank[4];
    }
    a   = wave_reduce(a);
    sz  = wave_reduce(sz);
    sz2 = wave_reduce(sz2);
    sp  = wave_reduce(sp);
    sp2 = wave_reduce(sp2);

    __shared__ float sdata[4][5];
    int lane = t & 63, wid = t >> 6;
    if (lane == 0) {
        sdata[wid][0] = a;  sdata[wid][1] = sz; sdata[wid][2] = sz2;
        sdata[wid][3] = sp; sdata[wid][4] = sp2;
    }
    __syncthreads();

    if (t == 0) {
        double A = 0, SZ = 0, SZ2 = 0, SP = 0, SP2 = 0;
        #pragma unroll
        for (int w = 0; w < 4; ++w) {
            A   += sdata[w][0];
            SZ  += sdata[w][1];
            SZ2 += sdata[w][2];
            SP  += sdata[w][3];
            SP2 += sdata[w][4];
        }
        // scalar tail (empty for N % 4 == 0, kept for generality)
        for (int i = tail_start; i < n; ++i) {
            float p = pred[i];
            if (lab[i] == 1) {
                double z = (double)MARGIN - (double)p;
                A += 1.0; SZ += z; SZ2 += z * z;
            } else {
                SP += (double)p; SP2 += (double)p * (double)p;
            }
        }
        double loss = A * SP2 + 2.0 * SZ * SP + SZ2 * ((double)n - A);
        out[0] = (float)loss;
    }
}

extern "C" void kernel_launch(void* const* d_in, const int* in_sizes, int n_in,
                              void* d_out, int out_size, void* d_ws, size_t ws_size,
                              hipStream_t stream)
{
    const float* pred = (const float*)d_in[0];
    const int*   lab  = (const int*)d_in[1];
    float*       out  = (float*)d_out;
    float*       ws   = (float*)d_ws;

    int n    = in_sizes[0];
    int nvec = n >> 2;
    int tail = nvec << 2;

    // pick nbanks (pow2, <=256) that fits in ws; fall back gracefully
    int bank_stride = BANK_STRIDE;
    size_t max_banks = ws_size / (bank_stride * sizeof(float));
    int nbanks = 1;
    if (max_banks == 0) { bank_stride = 5; nbanks = 1; }  // round-1 layout
    else { while (nbanks * 2 <= (int)max_banks && nbanks < 256) nbanks <<= 1; }

    // ws is re-poisoned to 0xAA before every timed launch — zero the banks
    hipMemsetAsync(ws, 0, (size_t)nbanks * bank_stride * sizeof(float), stream);

    const int block  = 256;
    const int blocks = 2048;   // 32 waves/CU across 256 CUs
    hinge2_reduce<<<blocks, block, 0, stream>>>(pred, lab, ws, nvec, nbanks, bank_stride);
    hinge2_final<<<1, block, 0, stream>>>(ws, pred, lab, out, n, tail, nbanks, bank_stride);
}

// Round 3
// 276.649 us; speedup vs baseline: 1.3768x; 1.0303x over previous
//
#include <hip/hip_runtime.h>

// loss = a*sum(pn^2) + 2*sum(z)*sum(pn) + sum(z^2)*(N - a)
//   z = (margin - p) on positives, pn = p on negatives, a = #positives.
// Streaming reduction: 256 MiB read, one scalar out. Memory-latency-bound.
//
// R2 post-mortem: VGPR_Count=36 proved the compiler collapsed the intended
// 8-deep load batch (needs 32 data VGPRs) to ~2-4 in flight; kernel was
// latency-bound at 2.3 TB/s effective. R3: one-shot kernel (no grid-stride
// loop), 16 straight-line 16-B loads per thread, __launch_bounds__(256,2)
// to lift the VGPR cap so the load batch survives scheduling.

constexpr float MARGIN = 1.0f;

#define BANK_STRIDE 32            // floats; 128 B = one L2 line per bank
#define BLOCK 256
#define GPT 8                     // float4-groups per thread
#define GROUPS_PER_BLOCK (BLOCK * GPT)   // 2048

__device__ __forceinline__ float wave_reduce(float v) {
    #pragma unroll
    for (int off = 32; off > 0; off >>= 1) v += __shfl_down(v, off, 64);
    return v;
}

__global__ __launch_bounds__(BLOCK, 2) void hinge2_reduce(
    const float* __restrict__ pred, const int* __restrict__ lab,
    float* __restrict__ ws, int nvec, int nbanks, int bank_stride)
{
    const float4* p4 = reinterpret_cast<const float4*>(pred);
    const int4*   l4 = reinterpret_cast<const int4*>(lab);

    float a = 0.f, sz = 0.f, sz2 = 0.f, sp = 0.f, sp2 = 0.f;

    #define ACC(px, lx) do {                         \
        float ispos = ((lx) == 1) ? 1.0f : 0.0f;     \
        float z  = ispos * (MARGIN - (px));          \
        a   += ispos;                                \
        sz  += z;                                    \
        sz2 += z * z;                                \
        float pn = ((lx) == 1) ? 0.0f : (px);        \
        sp  += pn;                                   \
        sp2 += pn * pn;                              \
    } while (0)
    #define ACC4(p, l) do {                          \
        ACC((p).x, (l).x); ACC((p).y, (l).y);        \
        ACC((p).z, (l).z); ACC((p).w, (l).w);        \
    } while (0)

    const int base = blockIdx.x * GROUPS_PER_BLOCK + threadIdx.x;

    if (base + (GPT - 1) * BLOCK < nvec) {
        // fast path: all 16 loads issued straight-line before any use
        float4 pv[GPT];
        int4   lv[GPT];
        #pragma unroll
        for (int k = 0; k < GPT; ++k) pv[k] = p4[base + k * BLOCK];
        #pragma unroll
        for (int k = 0; k < GPT; ++k) lv[k] = l4[base + k * BLOCK];
        #pragma unroll
        for (int k = 0; k < GPT; ++k) ACC4(pv[k], lv[k]);
    } else {
        // edge block: guarded per-group
        for (int k = 0; k < GPT; ++k) {
            int i = base + k * BLOCK;
            if (i < nvec) {
                float4 p = p4[i];
                int4   l = l4[i];
                ACC4(p, l);
            }
        }
    }
    #undef ACC4
    #undef ACC

    a   = wave_reduce(a);
    sz  = wave_reduce(sz);
    sz2 = wave_reduce(sz2);
    sp  = wave_reduce(sp);
    sp2 = wave_reduce(sp2);

    __shared__ float sdata[4][5];
    int lane = threadIdx.x & 63;
    int wid  = threadIdx.x >> 6;
    if (lane == 0) {
        sdata[wid][0] = a;
        sdata[wid][1] = sz;
        sdata[wid][2] = sz2;
        sdata[wid][3] = sp;
        sdata[wid][4] = sp2;
    }
    __syncthreads();

    if (threadIdx.x == 0) {
        float t0 = 0.f, t1 = 0.f, t2 = 0.f, t3 = 0.f, t4 = 0.f;
        #pragma unroll
        for (int w = 0; w < 4; ++w) {
            t0 += sdata[w][0];
            t1 += sdata[w][1];
            t2 += sdata[w][2];
            t3 += sdata[w][3];
            t4 += sdata[w][4];
        }
        float* bank = ws + (blockIdx.x & (nbanks - 1)) * bank_stride;
        atomicAdd(&bank[0], t0);
        atomicAdd(&bank[1], t1);
        atomicAdd(&bank[2], t2);
        atomicAdd(&bank[3], t3);
        atomicAdd(&bank[4], t4);
    }
}

__global__ __launch_bounds__(256) void hinge2_final(
    const float* __restrict__ ws,
    const float* __restrict__ pred, const int* __restrict__ lab,
    float* __restrict__ out, int n, int tail_start,
    int nbanks, int bank_stride)
{
    int t = threadIdx.x;
    float a = 0.f, sz = 0.f, sz2 = 0.f, sp = 0.f, sp2 = 0.f;
    for (int b = t; b < nbanks; b += 256) {
        const float* bank = ws + b * bank_stride;
        a   += bank[0];
        sz  += bank[1];
        sz2 += bank[2];
        sp  += bank[3];
        sp2 += bank[4];
    }
    a   = wave_reduce(a);
    sz  = wave_reduce(sz);
    sz2 = wave_reduce(sz2);
    sp  = wave_reduce(sp);
    sp2 = wave_reduce(sp2);

    __shared__ float sdata[4][5];
    int lane = t & 63, wid = t >> 6;
    if (lane == 0) {
        sdata[wid][0] = a;  sdata[wid][1] = sz; sdata[wid][2] = sz2;
        sdata[wid][3] = sp; sdata[wid][4] = sp2;
    }
    __syncthreads();

    if (t == 0) {
        double A = 0, SZ = 0, SZ2 = 0, SP = 0, SP2 = 0;
        #pragma unroll
        for (int w = 0; w < 4; ++w) {
            A   += sdata[w][0];
            SZ  += sdata[w][1];
            SZ2 += sdata[w][2];
            SP  += sdata[w][3];
            SP2 += sdata[w][4];
        }
        for (int i = tail_start; i < n; ++i) {
            float p = pred[i];
            if (lab[i] == 1) {
                double z = (double)MARGIN - (double)p;
                A += 1.0; SZ += z; SZ2 += z * z;
            } else {
                SP += (double)p; SP2 += (double)p * (double)p;
            }
        }
        double loss = A * SP2 + 2.0 * SZ * SP + SZ2 * ((double)n - A);
        out[0] = (float)loss;
    }
}

extern "C" void kernel_launch(void* const* d_in, const int* in_sizes, int n_in,
                              void* d_out, int out_size, void* d_ws, size_t ws_size,
                              hipStream_t stream)
{
    const float* pred = (const float*)d_in[0];
    const int*   lab  = (const int*)d_in[1];
    float*       out  = (float*)d_out;
    float*       ws   = (float*)d_ws;

    int n    = in_sizes[0];
    int nvec = n >> 2;          // float4 / int4 groups
    int tail = nvec << 2;

    int bank_stride = BANK_STRIDE;
    size_t max_banks = ws_size / (bank_stride * sizeof(float));
    int nbanks = 1;
    if (max_banks == 0) { bank_stride = 5; nbanks = 1; }
    else { while (nbanks * 2 <= (int)max_banks && nbanks < 256) nbanks <<= 1; }

    // ws is re-poisoned to 0xAA before every timed launch — zero the banks
    hipMemsetAsync(ws, 0, (size_t)nbanks * bank_stride * sizeof(float), stream);

    int blocks = (nvec + GROUPS_PER_BLOCK - 1) / GROUPS_PER_BLOCK;  // 4096 for N=2^25
    if (blocks < 1) blocks = 1;
    hinge2_reduce<<<blocks, BLOCK, 0, stream>>>(pred, lab, ws, nvec, nbanks, bank_stride);
    hinge2_final<<<1, BLOCK, 0, stream>>>(ws, pred, lab, out, n, tail, nbanks, bank_stride);
}

// Round 4
// 275.801 us; speedup vs baseline: 1.3810x; 1.0031x over previous
//
#include <hip/hip_runtime.h>

// loss = a*sum(pn^2) + 2*sum(z)*sum(pn) + sum(z^2)*(N - a)
//   z = (margin - p) on positives, pn = p on negatives, a = #positives.
// Streaming reduction: 256 MiB read, one scalar out. Memory-latency-bound.
//
// R3 post-mortem: VGPR_Count stayed 36 -> compiler re-interleaved the load
// batch (scheduler minimizes liveness; launch_bounds only raises the cap).
// R4: __builtin_amdgcn_sched_barrier(0) between the 16-load batch and the
// consume loop -- scheduler cannot sink loads past it, forcing 16 live load
// destinations = real 16-deep MLP per wave. Expect VGPR >= 120.

constexpr float MARGIN = 1.0f;

#define BANK_STRIDE 32            // floats; 128 B = one L2 line per bank
#define BLOCK 256
#define GPT 8                     // float4-groups per thread
#define GROUPS_PER_BLOCK (BLOCK * GPT)   // 2048

__device__ __forceinline__ float wave_reduce(float v) {
    #pragma unroll
    for (int off = 32; off > 0; off >>= 1) v += __shfl_down(v, off, 64);
    return v;
}

__global__ __launch_bounds__(BLOCK, 2) void hinge2_reduce(
    const float* __restrict__ pred, const int* __restrict__ lab,
    float* __restrict__ ws, int nvec, int nbanks, int bank_stride)
{
    const float4* p4 = reinterpret_cast<const float4*>(pred);
    const int4*   l4 = reinterpret_cast<const int4*>(lab);

    float a = 0.f, sz = 0.f, sz2 = 0.f, sp = 0.f, sp2 = 0.f;

    #define ACC(px, lx) do {                         \
        float ispos = ((lx) == 1) ? 1.0f : 0.0f;     \
        float z  = ispos * (MARGIN - (px));          \
        a   += ispos;                                \
        sz  += z;                                    \
        sz2 += z * z;                                \
        float pn = ((lx) == 1) ? 0.0f : (px);        \
        sp  += pn;                                   \
        sp2 += pn * pn;                              \
    } while (0)
    #define ACC4(p, l) do {                          \
        ACC((p).x, (l).x); ACC((p).y, (l).y);        \
        ACC((p).z, (l).z); ACC((p).w, (l).w);        \
    } while (0)

    const int base = blockIdx.x * GROUPS_PER_BLOCK + threadIdx.x;

    if (base + (GPT - 1) * BLOCK < nvec) {
        // issue all 16 loads; sched_barrier(0) pins them above the consumers
        float4 pv[GPT];
        int4   lv[GPT];
        #pragma unroll
        for (int k = 0; k < GPT; ++k) pv[k] = p4[base + k * BLOCK];
        #pragma unroll
        for (int k = 0; k < GPT; ++k) lv[k] = l4[base + k * BLOCK];
        __builtin_amdgcn_sched_barrier(0);   // no instruction may cross
        #pragma unroll
        for (int k = 0; k < GPT; ++k) ACC4(pv[k], lv[k]);
    } else {
        for (int k = 0; k < GPT; ++k) {
            int i = base + k * BLOCK;
            if (i < nvec) {
                float4 p = p4[i];
                int4   l = l4[i];
                ACC4(p, l);
            }
        }
    }
    #undef ACC4
    #undef ACC

    a   = wave_reduce(a);
    sz  = wave_reduce(sz);
    sz2 = wave_reduce(sz2);
    sp  = wave_reduce(sp);
    sp2 = wave_reduce(sp2);

    __shared__ float sdata[4][5];
    int lane = threadIdx.x & 63;
    int wid  = threadIdx.x >> 6;
    if (lane == 0) {
        sdata[wid][0] = a;
        sdata[wid][1] = sz;
        sdata[wid][2] = sz2;
        sdata[wid][3] = sp;
        sdata[wid][4] = sp2;
    }
    __syncthreads();

    if (threadIdx.x == 0) {
        float t0 = 0.f, t1 = 0.f, t2 = 0.f, t3 = 0.f, t4 = 0.f;
        #pragma unroll
        for (int w = 0; w < 4; ++w) {
            t0 += sdata[w][0];
            t1 += sdata[w][1];
            t2 += sdata[w][2];
            t3 += sdata[w][3];
            t4 += sdata[w][4];
        }
        float* bank = ws + (blockIdx.x & (nbanks - 1)) * bank_stride;
        atomicAdd(&bank[0], t0);
        atomicAdd(&bank[1], t1);
        atomicAdd(&bank[2], t2);
        atomicAdd(&bank[3], t3);
        atomicAdd(&bank[4], t4);
    }
}

__global__ __launch_bounds__(256) void hinge2_final(
    const float* __restrict__ ws,
    const float* __restrict__ pred, const int* __restrict__ lab,
    float* __restrict__ out, int n, int tail_start,
    int nbanks, int bank_stride)
{
    int t = threadIdx.x;
    float a = 0.f, sz = 0.f, sz2 = 0.f, sp = 0.f, sp2 = 0.f;
    for (int b = t; b < nbanks; b += 256) {
        const float* bank = ws + b * bank_stride;
        a   += bank[0];
        sz  += bank[1];
        sz2 += bank[2];
        sp  += bank[3];
        sp2 += bank[4];
    }
    a   = wave_reduce(a);
    sz  = wave_reduce(sz);
    sz2 = wave_reduce(sz2);
    sp  = wave_reduce(sp);
    sp2 = wave_reduce(sp2);

    __shared__ float sdata[4][5];
    int lane = t & 63, wid = t >> 6;
    if (lane == 0) {
        sdata[wid][0] = a;  sdata[wid][1] = sz; sdata[wid][2] = sz2;
        sdata[wid][3] = sp; sdata[wid][4] = sp2;
    }
    __syncthreads();

    if (t == 0) {
        double A = 0, SZ = 0, SZ2 = 0, SP = 0, SP2 = 0;
        #pragma unroll
        for (int w = 0; w < 4; ++w) {
            A   += sdata[w][0];
            SZ  += sdata[w][1];
            SZ2 += sdata[w][2];
            SP  += sdata[w][3];
            SP2 += sdata[w][4];
        }
        for (int i = tail_start; i < n; ++i) {
            float p = pred[i];
            if (lab[i] == 1) {
                double z = (double)MARGIN - (double)p;
                A += 1.0; SZ += z; SZ2 += z * z;
            } else {
                SP += (double)p; SP2 += (double)p * (double)p;
            }
        }
        double loss = A * SP2 + 2.0 * SZ * SP + SZ2 * ((double)n - A);
        out[0] = (float)loss;
    }
}

extern "C" void kernel_launch(void* const* d_in, const int* in_sizes, int n_in,
                              void* d_out, int out_size, void* d_ws, size_t ws_size,
                              hipStream_t stream)
{
    const float* pred = (const float*)d_in[0];
    const int*   lab  = (const int*)d_in[1];
    float*       out  = (float*)d_out;
    float*       ws   = (float*)d_ws;

    int n    = in_sizes[0];
    int nvec = n >> 2;          // float4 / int4 groups
    int tail = nvec << 2;

    int bank_stride = BANK_STRIDE;
    size_t max_banks = ws_size / (bank_stride * sizeof(float));
    int nbanks = 1;
    if (max_banks == 0) { bank_stride = 5; nbanks = 1; }
    else { while (nbanks * 2 <= (int)max_banks && nbanks < 256) nbanks <<= 1; }

    // ws is re-poisoned to 0xAA before every timed launch — zero the banks
    hipMemsetAsync(ws, 0, (size_t)nbanks * bank_stride * sizeof(float), stream);

    int blocks = (nvec + GROUPS_PER_BLOCK - 1) / GROUPS_PER_BLOCK;  // 4096 for N=2^25
    if (blocks < 1) blocks = 1;
    hinge2_reduce<<<blocks, BLOCK, 0, stream>>>(pred, lab, ws, nvec, nbanks, bank_stride);
    hinge2_final<<<1, BLOCK, 0, stream>>>(ws, pred, lab, out, n, tail, nbanks, bank_stride);
}